// Round 2
// baseline (436.328 us; speedup 1.0000x reference)
//
#include <hip/hip_runtime.h>

#define MT 48
#define TS 520          // tile row stride in shorts: 512 + 8 pad -> b128 R/W conflict-free
#define NROWS 262144
#define EPSV 1e-5f

typedef __attribute__((ext_vector_type(8))) short short8;
typedef __attribute__((ext_vector_type(4))) float floatx4;
typedef __attribute__((ext_vector_type(2))) float floatx2;
typedef __attribute__((ext_vector_type(4))) unsigned int uintx4;
typedef __attribute__((ext_vector_type(2))) unsigned int uintx2;

__device__ __forceinline__ unsigned short f2bf(float f) {
    unsigned u = __builtin_bit_cast(unsigned, f);
    u += 0x7fff + ((u >> 16) & 1);
    return (unsigned short)(u >> 16);
}
__device__ __forceinline__ float bf2f(short s) {
    unsigned u = ((unsigned)(unsigned short)s) << 16;
    return __builtin_bit_cast(float, u);
}
// packed f32x2 -> bf16x2, RNE (bit-identical to f2bf); 1 op for 2 elements
__device__ __forceinline__ unsigned cvtpk(float a, float b) {
    unsigned r;
    asm("v_cvt_pk_bf16_f32 %0, %1, %2" : "=v"(r) : "v"(a), "v"(b));
    return r;
}
// VOP3P packed f32 (2 elems/instr) — CDNA2+ (v_pk_add/mul/fma_f32)
__device__ __forceinline__ floatx2 pk_add(floatx2 a, floatx2 b) {
    floatx2 d; asm("v_pk_add_f32 %0, %1, %2" : "=v"(d) : "v"(a), "v"(b)); return d;
}
__device__ __forceinline__ floatx2 pk_mul(floatx2 a, floatx2 b) {
    floatx2 d; asm("v_pk_mul_f32 %0, %1, %2" : "=v"(d) : "v"(a), "v"(b)); return d;
}
__device__ __forceinline__ floatx2 pk_fma(floatx2 a, floatx2 b, floatx2 c) {
    floatx2 d; asm("v_pk_fma_f32 %0, %1, %2, %3" : "=v"(d) : "v"(a), "v"(b), "v"(c)); return d;
}
// DPP row_shr add (rocPRIM reduce pattern): after {1,2,4,8} lane l16==15 of
// each 16-group holds the full 16-lane sum.
template<int C>
__device__ __forceinline__ float dpp_add(float v) {
    int t = __builtin_amdgcn_update_dpp(0, __builtin_bit_cast(int, v), C, 0xf, 0xf, true);
    return v + __builtin_bit_cast(float, t);
}
__device__ __forceinline__ float red16(float v) {
    v = dpp_add<0x111>(v);   // row_shr:1
    v = dpp_add<0x112>(v);   // row_shr:2
    v = dpp_add<0x114>(v);   // row_shr:4
    v = dpp_add<0x118>(v);   // row_shr:8
    return v;                // valid in l16==15
}

// ===== lane-ordered weight layout (R4) with K-PERMUTATION for w2L/wh1L =====
// chunk[lane][j]; lane = quad*16+l16 holds B[k'][n], where k' is the PERMUTED
// k-index matching the h-tile layout: within each 128-col wave slab,
//   k' = w*128 + a*8 + b   <->   actual col = w*128 + b*16 + a   (a=0..15, b=0..7)
//   w1L  [64  chunks]  at 0       : c1 = (w*8 +nt)*2 +ks   (k unpermuted)
//   w2L  [512 chunks]  at 32768   : c2 = (w*16+ks)*8 +nt, n = w*128+nt*16+l16
//   wh1L [256 chunks]  at 294912  : c3 = (w*16+ks)*4 +nt, col = w*64+nt*16+l16
__global__ void convert_weights(const float* __restrict__ W1, const float* __restrict__ W2,
                                const float* __restrict__ Wh1, short* __restrict__ ws) {
    int idx = blockIdx.x * 256 + threadIdx.x;
    if (idx < 32768) {
        int j = idx & 7, lane = (idx >> 3) & 63, c = idx >> 9;
        int ks = c & 1, nt = (c >> 1) & 7, w = c >> 4;
        int k = ks * 32 + (lane >> 4) * 8 + j;
        int n = w * 128 + nt * 16 + (lane & 15);
        ws[idx] = (short)f2bf(W1[k * 512 + n]);
    } else if (idx < 32768 + 262144) {
        int jdx = idx - 32768;
        int j = jdx & 7, lane = (jdx >> 3) & 63, c = jdx >> 9;
        int nt = c & 7, ks = (c >> 3) & 15, w = c >> 7;
        int kp = ks * 32 + (lane >> 4) * 8 + j;                       // permuted k'
        int k  = (kp & 0x180) + ((kp & 7) << 4) + ((kp >> 3) & 15);   // actual k
        int n = w * 128 + nt * 16 + (lane & 15);
        ws[idx] = (short)f2bf(W2[k * 512 + n]);
    } else if (idx < 32768 + 262144 + 131072) {
        int jdx = idx - (32768 + 262144);
        int j = jdx & 7, lane = (jdx >> 3) & 63, c = jdx >> 9;
        int nt = c & 3, ks = (c >> 2) & 15, w = c >> 6;
        int kp = ks * 32 + (lane >> 4) * 8 + j;
        int k  = (kp & 0x180) + ((kp & 7) << 4) + ((kp >> 3) & 15);
        int col = w * 64 + nt * 16 + (lane & 15);
        int kk = col >> 6, d = col & 63;
        ws[idx] = (short)f2bf(Wh1[(kk * 512 + k) * 64 + d]);
    }
}

// R8 (this round): depth-1 double-buffered B prefetch in stages 2/3 with
// cross-stage hoist (stage-N+1's first chunks issued before stage-N's LN
// epilogue — global-only reads, no LDS hazard, latency hides under the
// epilogue + barriers); packed-f32 (v_pk_*) bias/stats/LN-apply; stats LDS
// restructured to psum/psq[wave][row] + negated-mean/rstd arrays so all pair
// accesses are natural b64. Theory: ~40% of R7 wall was vmcnt stall in the
// K-loops (8 L2 loads vs 116 cyc of MFMA cover, no pipelining, 2 waves/SIMD).
__global__ __launch_bounds__(256, 2) void fused_kernel(
    const float* __restrict__ z, const int* __restrict__ x, const int* __restrict__ y,
    const float* __restrict__ b1, const float* __restrict__ g1, const float* __restrict__ be1,
    const float* __restrict__ b2, const float* __restrict__ g2, const float* __restrict__ be2,
    const float* __restrict__ bh1, const float* __restrict__ Wh2, const float* __restrict__ bh2,
    const short* __restrict__ ws, float* __restrict__ out)
{
    __shared__ __align__(16) short tile[MT * TS];   // ~48.8 KB, reused: h1 -> h2 -> t
    __shared__ float psum[4][MT];                   // per-wave partial sums
    __shared__ float psq[4][MT];                    // per-wave partial sum-of-squares
    __shared__ float rmean[MT];                     // NEGATED row mean
    __shared__ float rrstd[MT];                     // row rstd

    int tid  = threadIdx.x;
    int wave = tid >> 6;
    int lane = tid & 63;
    int quad = lane >> 4;
    int l16  = lane & 15;
    int blk0 = blockIdx.x * MT;
    int nslab = wave * 128;

    const short* bbase1 = ws + wave * (16 * 512) + lane * 8;                      // w1L
    const short* bbase2 = ws + 32768 + wave * (16 * 8 * 512) + lane * 8;          // w2L
    const short* bbase3 = ws + 32768 + 262144 + wave * (16 * 4 * 512) + lane * 8; // wh1L

    floatx4 acc[3][8];   // 96 AGPRs — shared by stages 1, 2 AND 3 (union)
    short8 b2a[8], b2b[8];   // stage-2 B double buffer
    short8 b3a[4], b3b[4];   // stage-3 B double buffer

    // ================= stage 1: h1 = LN(z @ W1 + b1) -> leaky =================
#pragma unroll
    for (int mt = 0; mt < 3; mt++)
#pragma unroll
        for (int nt = 0; nt < 8; nt++) acc[mt][nt] = (floatx4){0.f, 0.f, 0.f, 0.f};

    __builtin_amdgcn_s_setprio(1);
#pragma unroll
    for (int ks = 0; ks < 2; ks++) {
        short8 afr[3];
#pragma unroll
        for (int mt = 0; mt < 3; mt++) {
            int row = blk0 + mt * 16 + l16;
            row = (row < NROWS) ? row : (NROWS - 1);      // clamp (last partial block)
            const float* zp = z + row * 64 + ks * 32 + quad * 8;
            floatx4 f0 = *(const floatx4*)zp;
            floatx4 f1 = *(const floatx4*)(zp + 4);
            uintx4 up;
            up[0] = cvtpk(f0[0], f0[1]); up[1] = cvtpk(f0[2], f0[3]);
            up[2] = cvtpk(f1[0], f1[1]); up[3] = cvtpk(f1[2], f1[3]);
            afr[mt] = __builtin_bit_cast(short8, up);
        }
#pragma unroll
        for (int nt = 0; nt < 8; nt++) {
            short8 b = *(const short8*)(bbase1 + (nt * 2 + ks) * 512);
#pragma unroll
            for (int mt = 0; mt < 3; mt++)
                acc[mt][nt] = __builtin_amdgcn_mfma_f32_16x16x32_bf16(afr[mt], b, acc[mt][nt], 0, 0, 0);
        }
    }
    __builtin_amdgcn_s_setprio(0);

    // ---- cross-stage prefetch: stage-2 ks=0 chunks (global-only, no LDS dep);
    // ---- latency hides under the whole stage-1 LN epilogue + 3 barriers.
#pragma unroll
    for (int nt = 0; nt < 8; nt++) b2a[nt] = *(const short8*)(bbase2 + nt * 512);

    // ---- bias + in-register LN stats (packed f32; DPP reduce, result in l16==15)
    {
        floatx2 s2[3][2] = {}, q2[3][2] = {};
#pragma unroll
        for (int nt = 0; nt < 8; nt++) {
            float bv = b1[nslab + nt * 16 + l16];
            floatx2 bb = {bv, bv};
#pragma unroll
            for (int mt = 0; mt < 3; mt++) {
                floatx2 v01 = {acc[mt][nt][0], acc[mt][nt][1]};
                floatx2 v23 = {acc[mt][nt][2], acc[mt][nt][3]};
                v01 = pk_add(v01, bb); v23 = pk_add(v23, bb);
                acc[mt][nt][0] = v01[0]; acc[mt][nt][1] = v01[1];
                acc[mt][nt][2] = v23[0]; acc[mt][nt][3] = v23[1];
                s2[mt][0] = pk_add(s2[mt][0], v01); q2[mt][0] = pk_fma(v01, v01, q2[mt][0]);
                s2[mt][1] = pk_add(s2[mt][1], v23); q2[mt][1] = pk_fma(v23, v23, q2[mt][1]);
            }
        }
#pragma unroll
        for (int mt = 0; mt < 3; mt++)
#pragma unroll
            for (int pr = 0; pr < 2; pr++) {
                s2[mt][pr][0] = red16(s2[mt][pr][0]); s2[mt][pr][1] = red16(s2[mt][pr][1]);
                q2[mt][pr][0] = red16(q2[mt][pr][0]); q2[mt][pr][1] = red16(q2[mt][pr][1]);
            }
        if (l16 == 15) {
#pragma unroll
            for (int mt = 0; mt < 3; mt++)
#pragma unroll
                for (int pr = 0; pr < 2; pr++) {
                    int row = mt * 16 + quad * 4 + pr * 2;
                    *(floatx2*)&psum[wave][row] = s2[mt][pr];
                    *(floatx2*)&psq[wave][row]  = q2[mt][pr];
                }
        }
    }
    __syncthreads();
    if (tid < MT) {
        float s = psum[0][tid] + psum[1][tid] + psum[2][tid] + psum[3][tid];
        float q = psq[0][tid] + psq[1][tid] + psq[2][tid] + psq[3][tid];
        float mean = s * (1.f / 512.f);
        float var  = q * (1.f / 512.f) - mean * mean;
        rmean[tid] = -mean;
        rrstd[tid] = rsqrtf(var + EPSV);
    }
    __syncthreads();
    {
        floatx2 nm[3][2], rs[3][2];
#pragma unroll
        for (int mt = 0; mt < 3; mt++)
#pragma unroll
            for (int pr = 0; pr < 2; pr++) {
                int row = mt * 16 + quad * 4 + pr * 2;
                nm[mt][pr] = *(const floatx2*)&rmean[row];
                rs[mt][pr] = *(const floatx2*)&rrstd[row];
            }
        floatx2 ggA[8], bbA[8];
#pragma unroll
        for (int nt = 0; nt < 8; nt++) {
            int col = nslab + nt * 16 + l16;
            float g = g1[col], be = be1[col];
            ggA[nt] = (floatx2){g, g}; bbA[nt] = (floatx2){be, be};
        }
#pragma unroll
        for (int mt = 0; mt < 3; mt++)
#pragma unroll
            for (int pr = 0; pr < 2; pr++) {
                float fa[8], fb[8];
#pragma unroll
                for (int nt = 0; nt < 8; nt++) {
                    floatx2 v = {acc[mt][nt][2 * pr], acc[mt][nt][2 * pr + 1]};
                    floatx2 t = pk_mul(pk_add(v, nm[mt][pr]), rs[mt][pr]);
                    floatx2 f = pk_fma(t, ggA[nt], bbA[nt]);
                    fa[nt] = fmaxf(f[0], 0.2f * f[0]);
                    fb[nt] = fmaxf(f[1], 0.2f * f[1]);
                }
                int row = mt * 16 + quad * 4 + pr * 2;
                uintx4 ua, ub;
                ua[0] = cvtpk(fa[0], fa[1]); ua[1] = cvtpk(fa[2], fa[3]);
                ua[2] = cvtpk(fa[4], fa[5]); ua[3] = cvtpk(fa[6], fa[7]);
                ub[0] = cvtpk(fb[0], fb[1]); ub[1] = cvtpk(fb[2], fb[3]);
                ub[2] = cvtpk(fb[4], fb[5]); ub[3] = cvtpk(fb[6], fb[7]);
                *(uintx4*)&tile[row * TS + nslab + l16 * 8]       = ua;
                *(uintx4*)&tile[(row + 1) * TS + nslab + l16 * 8] = ub;
            }
    }
    __syncthreads();

    // ================= stage 2: h2 = LN(h1 @ W2 + b2) -> leaky =================
#pragma unroll
    for (int mt = 0; mt < 3; mt++)
#pragma unroll
        for (int nt = 0; nt < 8; nt++) acc[mt][nt] = (floatx4){0.f, 0.f, 0.f, 0.f};

    __builtin_amdgcn_s_setprio(1);
#pragma unroll
    for (int ks = 0; ks < 16; ks += 2) {
        // prefetch ks+1 chunks while MFMAing ks
#pragma unroll
        for (int nt = 0; nt < 8; nt++)
            b2b[nt] = *(const short8*)(bbase2 + ((ks + 1) * 8 + nt) * 512);
        {
            short8 afr[3];
#pragma unroll
            for (int mt = 0; mt < 3; mt++)
                afr[mt] = *(const short8*)&tile[(mt * 16 + l16) * TS + ks * 32 + quad * 8];
#pragma unroll
            for (int nt = 0; nt < 8; nt++)
#pragma unroll
                for (int mt = 0; mt < 3; mt++)
                    acc[mt][nt] = __builtin_amdgcn_mfma_f32_16x16x32_bf16(afr[mt], b2a[nt], acc[mt][nt], 0, 0, 0);
        }
        if (ks + 2 < 16) {
#pragma unroll
            for (int nt = 0; nt < 8; nt++)
                b2a[nt] = *(const short8*)(bbase2 + ((ks + 2) * 8 + nt) * 512);
        }
        {
            short8 afr[3];
#pragma unroll
            for (int mt = 0; mt < 3; mt++)
                afr[mt] = *(const short8*)&tile[(mt * 16 + l16) * TS + (ks + 1) * 32 + quad * 8];
#pragma unroll
            for (int nt = 0; nt < 8; nt++)
#pragma unroll
                for (int mt = 0; mt < 3; mt++)
                    acc[mt][nt] = __builtin_amdgcn_mfma_f32_16x16x32_bf16(afr[mt], b2b[nt], acc[mt][nt], 0, 0, 0);
        }
    }
    __builtin_amdgcn_s_setprio(0);

    // ---- cross-stage prefetch: stage-3 ks=0 chunks
#pragma unroll
    for (int nt = 0; nt < 4; nt++) b3a[nt] = *(const short8*)(bbase3 + nt * 512);

    {
        floatx2 s2[3][2] = {}, q2[3][2] = {};
#pragma unroll
        for (int nt = 0; nt < 8; nt++) {
            float bv = b2[nslab + nt * 16 + l16];
            floatx2 bb = {bv, bv};
#pragma unroll
            for (int mt = 0; mt < 3; mt++) {
                floatx2 v01 = {acc[mt][nt][0], acc[mt][nt][1]};
                floatx2 v23 = {acc[mt][nt][2], acc[mt][nt][3]};
                v01 = pk_add(v01, bb); v23 = pk_add(v23, bb);
                acc[mt][nt][0] = v01[0]; acc[mt][nt][1] = v01[1];
                acc[mt][nt][2] = v23[0]; acc[mt][nt][3] = v23[1];
                s2[mt][0] = pk_add(s2[mt][0], v01); q2[mt][0] = pk_fma(v01, v01, q2[mt][0]);
                s2[mt][1] = pk_add(s2[mt][1], v23); q2[mt][1] = pk_fma(v23, v23, q2[mt][1]);
            }
        }
#pragma unroll
        for (int mt = 0; mt < 3; mt++)
#pragma unroll
            for (int pr = 0; pr < 2; pr++) {
                s2[mt][pr][0] = red16(s2[mt][pr][0]); s2[mt][pr][1] = red16(s2[mt][pr][1]);
                q2[mt][pr][0] = red16(q2[mt][pr][0]); q2[mt][pr][1] = red16(q2[mt][pr][1]);
            }
        if (l16 == 15) {
#pragma unroll
            for (int mt = 0; mt < 3; mt++)
#pragma unroll
                for (int pr = 0; pr < 2; pr++) {
                    int row = mt * 16 + quad * 4 + pr * 2;
                    *(floatx2*)&psum[wave][row] = s2[mt][pr];
                    *(floatx2*)&psq[wave][row]  = q2[mt][pr];
                }
        }
    }
    __syncthreads();
    if (tid < MT) {
        float s = psum[0][tid] + psum[1][tid] + psum[2][tid] + psum[3][tid];
        float q = psq[0][tid] + psq[1][tid] + psq[2][tid] + psq[3][tid];
        float mean = s * (1.f / 512.f);
        float var  = q * (1.f / 512.f) - mean * mean;
        rmean[tid] = -mean;
        rrstd[tid] = rsqrtf(var + EPSV);
    }
    __syncthreads();
    {
        floatx2 nm[3][2], rs[3][2];
#pragma unroll
        for (int mt = 0; mt < 3; mt++)
#pragma unroll
            for (int pr = 0; pr < 2; pr++) {
                int row = mt * 16 + quad * 4 + pr * 2;
                nm[mt][pr] = *(const floatx2*)&rmean[row];
                rs[mt][pr] = *(const floatx2*)&rrstd[row];
            }
        floatx2 ggA[8], bbA[8];
#pragma unroll
        for (int nt = 0; nt < 8; nt++) {
            int col = nslab + nt * 16 + l16;
            float g = g2[col], be = be2[col];
            ggA[nt] = (floatx2){g, g}; bbA[nt] = (floatx2){be, be};
        }
#pragma unroll
        for (int mt = 0; mt < 3; mt++)
#pragma unroll
            for (int pr = 0; pr < 2; pr++) {
                float fa[8], fb[8];
#pragma unroll
                for (int nt = 0; nt < 8; nt++) {
                    floatx2 v = {acc[mt][nt][2 * pr], acc[mt][nt][2 * pr + 1]};
                    floatx2 t = pk_mul(pk_add(v, nm[mt][pr]), rs[mt][pr]);
                    floatx2 f = pk_fma(t, ggA[nt], bbA[nt]);
                    fa[nt] = fmaxf(f[0], 0.2f * f[0]);
                    fb[nt] = fmaxf(f[1], 0.2f * f[1]);
                }
                int row = mt * 16 + quad * 4 + pr * 2;
                uintx4 ua, ub;
                ua[0] = cvtpk(fa[0], fa[1]); ua[1] = cvtpk(fa[2], fa[3]);
                ua[2] = cvtpk(fa[4], fa[5]); ua[3] = cvtpk(fa[6], fa[7]);
                ub[0] = cvtpk(fb[0], fb[1]); ub[1] = cvtpk(fb[2], fb[3]);
                ub[2] = cvtpk(fb[4], fb[5]); ub[3] = cvtpk(fb[6], fb[7]);
                *(uintx4*)&tile[row * TS + nslab + l16 * 8]       = ua;
                *(uintx4*)&tile[(row + 1) * TS + nslab + l16 * 8] = ub;
            }
    }
    __syncthreads();

    // ===== stage 3: t[k] = relu(h2 @ Wh1[k] + bh1[k]), all 4 heads =====
    // acc[mt][0..3] REUSED (dead after stage-2 LN write) -> no extra AGPRs
#pragma unroll
    for (int mt = 0; mt < 3; mt++)
#pragma unroll
        for (int nt = 0; nt < 4; nt++) acc[mt][nt] = (floatx4){0.f, 0.f, 0.f, 0.f};

    __builtin_amdgcn_s_setprio(1);
#pragma unroll
    for (int ks = 0; ks < 16; ks += 2) {
#pragma unroll
        for (int nt = 0; nt < 4; nt++)
            b3b[nt] = *(const short8*)(bbase3 + ((ks + 1) * 4 + nt) * 512);
        {
            short8 afr[3];
#pragma unroll
            for (int mt = 0; mt < 3; mt++)
                afr[mt] = *(const short8*)&tile[(mt * 16 + l16) * TS + ks * 32 + quad * 8];
#pragma unroll
            for (int nt = 0; nt < 4; nt++)
#pragma unroll
                for (int mt = 0; mt < 3; mt++)
                    acc[mt][nt] = __builtin_amdgcn_mfma_f32_16x16x32_bf16(afr[mt], b3a[nt], acc[mt][nt], 0, 0, 0);
        }
        if (ks + 2 < 16) {
#pragma unroll
            for (int nt = 0; nt < 4; nt++)
                b3a[nt] = *(const short8*)(bbase3 + ((ks + 2) * 4 + nt) * 512);
        }
        {
            short8 afr[3];
#pragma unroll
            for (int mt = 0; mt < 3; mt++)
                afr[mt] = *(const short8*)&tile[(mt * 16 + l16) * TS + (ks + 1) * 32 + quad * 8];
#pragma unroll
            for (int nt = 0; nt < 4; nt++)
#pragma unroll
                for (int mt = 0; mt < 3; mt++)
                    acc[mt][nt] = __builtin_amdgcn_mfma_f32_16x16x32_bf16(afr[mt], b3b[nt], acc[mt][nt], 0, 0, 0);
        }
    }
    __builtin_amdgcn_s_setprio(0);
    __syncthreads();   // all stage-3 tile reads done before t overwrites it
    {
        float bh1v[4];
#pragma unroll
        for (int nt = 0; nt < 4; nt++) bh1v[nt] = bh1[wave * 64 + nt * 16 + l16];
#pragma unroll
        for (int mt = 0; mt < 3; mt++)
#pragma unroll
            for (int r2 = 0; r2 < 4; r2++) {
                int row = mt * 16 + quad * 4 + r2;
                float f[4];
#pragma unroll
                for (int nt = 0; nt < 4; nt++) {
                    float v = acc[mt][nt][r2] + bh1v[nt];
                    f[nt] = (v > 0.f) ? v : 0.f;
                }
                uintx2 up = {cvtpk(f[0], f[1]), cvtpk(f[2], f[3])};
                // permuted t-layout: col' = wave*64 + l16*4 + nt  (value is t[d=nt*16+l16])
                *(uintx2*)&tile[row * TS + wave * 64 + l16 * 4] = up;
            }
    }
    __syncthreads();

    // ===== stage 4: per-row head select, logits, softmax (4 threads/row) =====
    // permuted t-layout: thread `is` covers l16 in [4is, 4is+4), nt 0..3 ->
    // 16 contiguous shorts at col' = kk*64 + 16*is; element e maps to
    // d(e) = (e&3)*16 + 4*is + (e>>2)  (ta), d+2 (tb).
    {
        int r = tid >> 2, is = tid & 3;          // r in 0..63, rows 0..47 valid
        if (r < MT) {
            int grow = blk0 + r;
            int gsafe = (grow < NROWS) ? grow : (NROWS - 1);
            int kk = 2 * x[gsafe] + y[gsafe];
            const short* tp = &tile[r * TS + kk * 64 + is * 16];
            short8 ta = *(const short8*)tp;
            short8 tb = *(const short8*)(tp + 8);
            const float* wp = Wh2 + kk * 256;
            float lg0 = 0.f, lg1 = 0.f, lg2 = 0.f, lg3 = 0.f;
#pragma unroll
            for (int e = 0; e < 8; e++) {
                int d0 = (e & 3) * 16 + 4 * is + (e >> 2);
                float t0 = bf2f(ta[e]);
                floatx4 w0 = *(const floatx4*)(wp + d0 * 4);
                float t1 = bf2f(tb[e]);
                floatx4 w1 = *(const floatx4*)(wp + (d0 + 2) * 4);
                lg0 += t0 * w0[0] + t1 * w1[0];
                lg1 += t0 * w0[1] + t1 * w1[1];
                lg2 += t0 * w0[2] + t1 * w1[2];
                lg3 += t0 * w0[3] + t1 * w1[3];
            }
#pragma unroll
            for (int off = 1; off < 4; off <<= 1) {
                lg0 += __shfl_xor(lg0, off, 64);
                lg1 += __shfl_xor(lg1, off, 64);
                lg2 += __shfl_xor(lg2, off, 64);
                lg3 += __shfl_xor(lg3, off, 64);
            }
            if (is == 0 && grow < NROWS) {
                lg0 += bh2[kk * 4 + 0]; lg1 += bh2[kk * 4 + 1];
                lg2 += bh2[kk * 4 + 2]; lg3 += bh2[kk * 4 + 3];
                float m = fmaxf(fmaxf(lg0, lg1), fmaxf(lg2, lg3));
                float e0 = __expf(lg0 - m), e1 = __expf(lg1 - m);
                float e2 = __expf(lg2 - m), e3 = __expf(lg3 - m);
                float inv = 1.f / (e0 + e1 + e2 + e3);
                floatx4 o = {e0 * inv, e1 * inv, e2 * inv, e3 * inv};
                *(floatx4*)(out + grow * 4) = o;
            }
        }
    }
}

extern "C" void kernel_launch(void* const* d_in, const int* in_sizes, int n_in,
                              void* d_out, int out_size, void* d_ws, size_t ws_size,
                              hipStream_t stream) {
    const float* z   = (const float*)d_in[0];
    const int*   x   = (const int*)d_in[1];
    const int*   y   = (const int*)d_in[2];
    const float* W1  = (const float*)d_in[3];
    const float* b1  = (const float*)d_in[4];
    const float* g1  = (const float*)d_in[5];
    const float* be1 = (const float*)d_in[6];
    const float* W2  = (const float*)d_in[7];
    const float* b2  = (const float*)d_in[8];
    const float* g2  = (const float*)d_in[9];
    const float* be2 = (const float*)d_in[10];
    const float* Wh1 = (const float*)d_in[11];
    const float* bh1 = (const float*)d_in[12];
    const float* Wh2 = (const float*)d_in[13];
    const float* bh2 = (const float*)d_in[14];
    short* ws = (short*)d_ws;
    float* out = (float*)d_out;

    hipLaunchKernelGGL(convert_weights, dim3(1664), dim3(256), 0, stream, W1, W2, Wh1, ws);
    hipLaunchKernelGGL(fused_kernel, dim3((NROWS + MT - 1) / MT), dim3(256), 0, stream,
                       z, x, y, b1, g1, be1, b2, g2, be2, bh1, Wh2, bh2,
                       (const short*)ws, out);
}

// Round 4
// 363.952 us; speedup vs baseline: 1.1989x; 1.1989x over previous
//
#include <hip/hip_runtime.h>

#define MT 64           // rows per block; 262144/64 = 4096 blocks exactly (no partial clamp)
#define MTM 4           // 16-row m-tiles per block
#define TS 520          // tile row stride in shorts: 512 + 8 pad -> b128 R/W conflict-free
#define NROWS 262144
#define EPSV 1e-5f

typedef __attribute__((ext_vector_type(8))) short short8;
typedef __attribute__((ext_vector_type(4))) float floatx4;
typedef __attribute__((ext_vector_type(2))) float floatx2;
typedef __attribute__((ext_vector_type(4))) unsigned int uintx4;
typedef __attribute__((ext_vector_type(2))) unsigned int uintx2;

__device__ __forceinline__ unsigned short f2bf(float f) {
    unsigned u = __builtin_bit_cast(unsigned, f);
    u += 0x7fff + ((u >> 16) & 1);
    return (unsigned short)(u >> 16);
}
__device__ __forceinline__ float bf2f(short s) {
    unsigned u = ((unsigned)(unsigned short)s) << 16;
    return __builtin_bit_cast(float, u);
}
// packed f32x2 -> bf16x2, RNE (bit-identical to f2bf); 1 op for 2 elements
__device__ __forceinline__ unsigned cvtpk(float a, float b) {
    unsigned r;
    asm("v_cvt_pk_bf16_f32 %0, %1, %2" : "=v"(r) : "v"(a), "v"(b));
    return r;
}
// VOP3P packed f32 (2 elems/instr)
__device__ __forceinline__ floatx2 pk_add(floatx2 a, floatx2 b) {
    floatx2 d; asm("v_pk_add_f32 %0, %1, %2" : "=v"(d) : "v"(a), "v"(b)); return d;
}
__device__ __forceinline__ floatx2 pk_mul(floatx2 a, floatx2 b) {
    floatx2 d; asm("v_pk_mul_f32 %0, %1, %2" : "=v"(d) : "v"(a), "v"(b)); return d;
}
__device__ __forceinline__ floatx2 pk_fma(floatx2 a, floatx2 b, floatx2 c) {
    floatx2 d; asm("v_pk_fma_f32 %0, %1, %2, %3" : "=v"(d) : "v"(a), "v"(b), "v"(c)); return d;
}
// DPP row_shr add: after {1,2,4,8} lane l16==15 of each 16-group holds the sum
template<int C>
__device__ __forceinline__ float dpp_add(float v) {
    int t = __builtin_amdgcn_update_dpp(0, __builtin_bit_cast(int, v), C, 0xf, 0xf, true);
    return v + __builtin_bit_cast(float, t);
}
__device__ __forceinline__ float red16(float v) {
    v = dpp_add<0x111>(v);
    v = dpp_add<0x112>(v);
    v = dpp_add<0x114>(v);
    v = dpp_add<0x118>(v);
    return v;
}

// ===== lane-ordered weight layout (R4) with K-PERMUTATION for w2L/wh1L =====
// (unchanged; MT-independent — keyed to per-wave 128-col slabs)
__global__ void convert_weights(const float* __restrict__ W1, const float* __restrict__ W2,
                                const float* __restrict__ Wh1, short* __restrict__ ws) {
    int idx = blockIdx.x * 256 + threadIdx.x;
    if (idx < 32768) {
        int j = idx & 7, lane = (idx >> 3) & 63, c = idx >> 9;
        int ks = c & 1, nt = (c >> 1) & 7, w = c >> 4;
        int k = ks * 32 + (lane >> 4) * 8 + j;
        int n = w * 128 + nt * 16 + (lane & 15);
        ws[idx] = (short)f2bf(W1[k * 512 + n]);
    } else if (idx < 32768 + 262144) {
        int jdx = idx - 32768;
        int j = jdx & 7, lane = (jdx >> 3) & 63, c = jdx >> 9;
        int nt = c & 7, ks = (c >> 3) & 15, w = c >> 7;
        int kp = ks * 32 + (lane >> 4) * 8 + j;                       // permuted k'
        int k  = (kp & 0x180) + ((kp & 7) << 4) + ((kp >> 3) & 15);   // actual k
        int n = w * 128 + nt * 16 + (lane & 15);
        ws[idx] = (short)f2bf(W2[k * 512 + n]);
    } else if (idx < 32768 + 262144 + 131072) {
        int jdx = idx - (32768 + 262144);
        int j = jdx & 7, lane = (jdx >> 3) & 63, c = jdx >> 9;
        int nt = c & 3, ks = (c >> 2) & 15, w = c >> 6;
        int kp = ks * 32 + (lane >> 4) * 8 + j;
        int k  = (kp & 0x180) + ((kp & 7) << 4) + ((kp >> 3) & 15);
        int col = w * 64 + nt * 16 + (lane & 15);
        int kk = col >> 6, d = col & 63;
        ws[idx] = (short)f2bf(Wh1[(kk * 512 + k) * 64 + d]);
    }
}

// R9/R10: the kernel is L2-BANDWIDTH bound on weight re-streaming
// (208KB/wave/pass -> 1.66MB/CU/pass = ~30K cyc at 56B/cyc/CU vs 42.5K wall).
// Fix = amortize weights over more rows: MT 48 -> 64 (traffic/row x0.75,
// 4096 exact blocks, clamps removed). acc 4x8 = 128 AGPR + ~110 VGPR < 256
// -> still 2 waves/SIMD; LDS 69KB x2 = 138 <= 160. R2's explicit B
// double-buffer REVERTED (latency fix for a bandwidth problem: -10us, +8
// VGPR); packed-f32 epilogue + DPP reductions kept (VALU cycles -20%, proven).
__global__ __launch_bounds__(256, 2) void fused_kernel(
    const float* __restrict__ z, const int* __restrict__ x, const int* __restrict__ y,
    const float* __restrict__ b1, const float* __restrict__ g1, const float* __restrict__ be1,
    const float* __restrict__ b2, const float* __restrict__ g2, const float* __restrict__ be2,
    const float* __restrict__ bh1, const float* __restrict__ Wh2, const float* __restrict__ bh2,
    const short* __restrict__ ws, float* __restrict__ out)
{
    __shared__ __align__(16) short tile[MT * TS];   // 65 KB, reused: h1 -> h2 -> t
    __shared__ float psum[4][MT];
    __shared__ float psq[4][MT];
    __shared__ float rmean[MT];                     // NEGATED row mean
    __shared__ float rrstd[MT];

    int tid  = threadIdx.x;
    int wave = tid >> 6;
    int lane = tid & 63;
    int quad = lane >> 4;
    int l16  = lane & 15;
    int blk0 = blockIdx.x * MT;
    int nslab = wave * 128;

    const short* bbase1 = ws + wave * (16 * 512) + lane * 8;                      // w1L
    const short* bbase2 = ws + 32768 + wave * (16 * 8 * 512) + lane * 8;          // w2L
    const short* bbase3 = ws + 32768 + 262144 + wave * (16 * 4 * 512) + lane * 8; // wh1L

    floatx4 acc[MTM][8];   // 128 AGPRs — shared by stages 1, 2 AND 3 (union)

    // ================= stage 1: h1 = LN(z @ W1 + b1) -> leaky =================
#pragma unroll
    for (int mt = 0; mt < MTM; mt++)
#pragma unroll
        for (int nt = 0; nt < 8; nt++) acc[mt][nt] = (floatx4){0.f, 0.f, 0.f, 0.f};

    __builtin_amdgcn_s_setprio(1);
#pragma unroll
    for (int ks = 0; ks < 2; ks++) {
        short8 afr[MTM];
#pragma unroll
        for (int mt = 0; mt < MTM; mt++) {
            int row = blk0 + mt * 16 + l16;
            const float* zp = z + row * 64 + ks * 32 + quad * 8;
            floatx4 f0 = *(const floatx4*)zp;
            floatx4 f1 = *(const floatx4*)(zp + 4);
            uintx4 up;
            up[0] = cvtpk(f0[0], f0[1]); up[1] = cvtpk(f0[2], f0[3]);
            up[2] = cvtpk(f1[0], f1[1]); up[3] = cvtpk(f1[2], f1[3]);
            afr[mt] = __builtin_bit_cast(short8, up);
        }
#pragma unroll
        for (int nt = 0; nt < 8; nt++) {
            short8 b = *(const short8*)(bbase1 + (nt * 2 + ks) * 512);
#pragma unroll
            for (int mt = 0; mt < MTM; mt++)
                acc[mt][nt] = __builtin_amdgcn_mfma_f32_16x16x32_bf16(afr[mt], b, acc[mt][nt], 0, 0, 0);
        }
    }
    __builtin_amdgcn_s_setprio(0);

    // ---- bias + in-register LN stats (packed f32; DPP reduce, result in l16==15)
    {
        floatx2 s2[MTM][2] = {}, q2[MTM][2] = {};
#pragma unroll
        for (int nt = 0; nt < 8; nt++) {
            float bv = b1[nslab + nt * 16 + l16];
            floatx2 bb = {bv, bv};
#pragma unroll
            for (int mt = 0; mt < MTM; mt++) {
                floatx2 v01 = {acc[mt][nt][0], acc[mt][nt][1]};
                floatx2 v23 = {acc[mt][nt][2], acc[mt][nt][3]};
                v01 = pk_add(v01, bb); v23 = pk_add(v23, bb);
                acc[mt][nt][0] = v01[0]; acc[mt][nt][1] = v01[1];
                acc[mt][nt][2] = v23[0]; acc[mt][nt][3] = v23[1];
                s2[mt][0] = pk_add(s2[mt][0], v01); q2[mt][0] = pk_fma(v01, v01, q2[mt][0]);
                s2[mt][1] = pk_add(s2[mt][1], v23); q2[mt][1] = pk_fma(v23, v23, q2[mt][1]);
            }
        }
#pragma unroll
        for (int mt = 0; mt < MTM; mt++)
#pragma unroll
            for (int pr = 0; pr < 2; pr++) {
                s2[mt][pr][0] = red16(s2[mt][pr][0]); s2[mt][pr][1] = red16(s2[mt][pr][1]);
                q2[mt][pr][0] = red16(q2[mt][pr][0]); q2[mt][pr][1] = red16(q2[mt][pr][1]);
            }
        if (l16 == 15) {
#pragma unroll
            for (int mt = 0; mt < MTM; mt++)
#pragma unroll
                for (int pr = 0; pr < 2; pr++) {
                    int row = mt * 16 + quad * 4 + pr * 2;
                    *(floatx2*)&psum[wave][row] = s2[mt][pr];
                    *(floatx2*)&psq[wave][row]  = q2[mt][pr];
                }
        }
    }
    __syncthreads();
    if (tid < MT) {
        float s = psum[0][tid] + psum[1][tid] + psum[2][tid] + psum[3][tid];
        float q = psq[0][tid] + psq[1][tid] + psq[2][tid] + psq[3][tid];
        float mean = s * (1.f / 512.f);
        float var  = q * (1.f / 512.f) - mean * mean;
        rmean[tid] = -mean;
        rrstd[tid] = rsqrtf(var + EPSV);
    }
    __syncthreads();
    {
        floatx2 nm[MTM][2], rs[MTM][2];
#pragma unroll
        for (int mt = 0; mt < MTM; mt++)
#pragma unroll
            for (int pr = 0; pr < 2; pr++) {
                int row = mt * 16 + quad * 4 + pr * 2;
                nm[mt][pr] = *(const floatx2*)&rmean[row];
                rs[mt][pr] = *(const floatx2*)&rrstd[row];
            }
        floatx2 ggA[8], bbA[8];
#pragma unroll
        for (int nt = 0; nt < 8; nt++) {
            int col = nslab + nt * 16 + l16;
            float g = g1[col], be = be1[col];
            ggA[nt] = (floatx2){g, g}; bbA[nt] = (floatx2){be, be};
        }
#pragma unroll
        for (int mt = 0; mt < MTM; mt++)
#pragma unroll
            for (int pr = 0; pr < 2; pr++) {
                float fa[8], fb[8];
#pragma unroll
                for (int nt = 0; nt < 8; nt++) {
                    floatx2 v = {acc[mt][nt][2 * pr], acc[mt][nt][2 * pr + 1]};
                    floatx2 t = pk_mul(pk_add(v, nm[mt][pr]), rs[mt][pr]);
                    floatx2 f = pk_fma(t, ggA[nt], bbA[nt]);
                    fa[nt] = fmaxf(f[0], 0.2f * f[0]);
                    fb[nt] = fmaxf(f[1], 0.2f * f[1]);
                }
                int row = mt * 16 + quad * 4 + pr * 2;
                uintx4 ua, ub;
                ua[0] = cvtpk(fa[0], fa[1]); ua[1] = cvtpk(fa[2], fa[3]);
                ua[2] = cvtpk(fa[4], fa[5]); ua[3] = cvtpk(fa[6], fa[7]);
                ub[0] = cvtpk(fb[0], fb[1]); ub[1] = cvtpk(fb[2], fb[3]);
                ub[2] = cvtpk(fb[4], fb[5]); ub[3] = cvtpk(fb[6], fb[7]);
                *(uintx4*)&tile[row * TS + nslab + l16 * 8]       = ua;
                *(uintx4*)&tile[(row + 1) * TS + nslab + l16 * 8] = ub;
            }
    }
    __syncthreads();

    // ================= stage 2: h2 = LN(h1 @ W2 + b2) -> leaky =================
#pragma unroll
    for (int mt = 0; mt < MTM; mt++)
#pragma unroll
        for (int nt = 0; nt < 8; nt++) acc[mt][nt] = (floatx4){0.f, 0.f, 0.f, 0.f};

    __builtin_amdgcn_s_setprio(1);
    for (int ks = 0; ks < 16; ks++) {
        short8 afr[MTM];
#pragma unroll
        for (int mt = 0; mt < MTM; mt++)
            afr[mt] = *(const short8*)&tile[(mt * 16 + l16) * TS + ks * 32 + quad * 8];
#pragma unroll
        for (int nt = 0; nt < 8; nt++) {
            short8 b = *(const short8*)(bbase2 + (ks * 8 + nt) * 512);
#pragma unroll
            for (int mt = 0; mt < MTM; mt++)
                acc[mt][nt] = __builtin_amdgcn_mfma_f32_16x16x32_bf16(afr[mt], b, acc[mt][nt], 0, 0, 0);
        }
    }
    __builtin_amdgcn_s_setprio(0);
    {
        floatx2 s2[MTM][2] = {}, q2[MTM][2] = {};
#pragma unroll
        for (int nt = 0; nt < 8; nt++) {
            float bv = b2[nslab + nt * 16 + l16];
            floatx2 bb = {bv, bv};
#pragma unroll
            for (int mt = 0; mt < MTM; mt++) {
                floatx2 v01 = {acc[mt][nt][0], acc[mt][nt][1]};
                floatx2 v23 = {acc[mt][nt][2], acc[mt][nt][3]};
                v01 = pk_add(v01, bb); v23 = pk_add(v23, bb);
                acc[mt][nt][0] = v01[0]; acc[mt][nt][1] = v01[1];
                acc[mt][nt][2] = v23[0]; acc[mt][nt][3] = v23[1];
                s2[mt][0] = pk_add(s2[mt][0], v01); q2[mt][0] = pk_fma(v01, v01, q2[mt][0]);
                s2[mt][1] = pk_add(s2[mt][1], v23); q2[mt][1] = pk_fma(v23, v23, q2[mt][1]);
            }
        }
#pragma unroll
        for (int mt = 0; mt < MTM; mt++)
#pragma unroll
            for (int pr = 0; pr < 2; pr++) {
                s2[mt][pr][0] = red16(s2[mt][pr][0]); s2[mt][pr][1] = red16(s2[mt][pr][1]);
                q2[mt][pr][0] = red16(q2[mt][pr][0]); q2[mt][pr][1] = red16(q2[mt][pr][1]);
            }
        if (l16 == 15) {
#pragma unroll
            for (int mt = 0; mt < MTM; mt++)
#pragma unroll
                for (int pr = 0; pr < 2; pr++) {
                    int row = mt * 16 + quad * 4 + pr * 2;
                    *(floatx2*)&psum[wave][row] = s2[mt][pr];
                    *(floatx2*)&psq[wave][row]  = q2[mt][pr];
                }
        }
    }
    __syncthreads();
    if (tid < MT) {
        float s = psum[0][tid] + psum[1][tid] + psum[2][tid] + psum[3][tid];
        float q = psq[0][tid] + psq[1][tid] + psq[2][tid] + psq[3][tid];
        float mean = s * (1.f / 512.f);
        float var  = q * (1.f / 512.f) - mean * mean;
        rmean[tid] = -mean;
        rrstd[tid] = rsqrtf(var + EPSV);
    }
    __syncthreads();
    {
        floatx2 nm[MTM][2], rs[MTM][2];
#pragma unroll
        for (int mt = 0; mt < MTM; mt++)
#pragma unroll
            for (int pr = 0; pr < 2; pr++) {
                int row = mt * 16 + quad * 4 + pr * 2;
                nm[mt][pr] = *(const floatx2*)&rmean[row];
                rs[mt][pr] = *(const floatx2*)&rrstd[row];
            }
        floatx2 ggA[8], bbA[8];
#pragma unroll
        for (int nt = 0; nt < 8; nt++) {
            int col = nslab + nt * 16 + l16;
            float g = g2[col], be = be2[col];
            ggA[nt] = (floatx2){g, g}; bbA[nt] = (floatx2){be, be};
        }
#pragma unroll
        for (int mt = 0; mt < MTM; mt++)
#pragma unroll
            for (int pr = 0; pr < 2; pr++) {
                float fa[8], fb[8];
#pragma unroll
                for (int nt = 0; nt < 8; nt++) {
                    floatx2 v = {acc[mt][nt][2 * pr], acc[mt][nt][2 * pr + 1]};
                    floatx2 t = pk_mul(pk_add(v, nm[mt][pr]), rs[mt][pr]);
                    floatx2 f = pk_fma(t, ggA[nt], bbA[nt]);
                    fa[nt] = fmaxf(f[0], 0.2f * f[0]);
                    fb[nt] = fmaxf(f[1], 0.2f * f[1]);
                }
                int row = mt * 16 + quad * 4 + pr * 2;
                uintx4 ua, ub;
                ua[0] = cvtpk(fa[0], fa[1]); ua[1] = cvtpk(fa[2], fa[3]);
                ua[2] = cvtpk(fa[4], fa[5]); ua[3] = cvtpk(fa[6], fa[7]);
                ub[0] = cvtpk(fb[0], fb[1]); ub[1] = cvtpk(fb[2], fb[3]);
                ub[2] = cvtpk(fb[4], fb[5]); ub[3] = cvtpk(fb[6], fb[7]);
                *(uintx4*)&tile[row * TS + nslab + l16 * 8]       = ua;
                *(uintx4*)&tile[(row + 1) * TS + nslab + l16 * 8] = ub;
            }
    }
    __syncthreads();

    // ===== stage 3: t[k] = relu(h2 @ Wh1[k] + bh1[k]), all 4 heads =====
    // acc[mt][0..3] REUSED (dead after stage-2 LN write) -> no extra AGPRs
#pragma unroll
    for (int mt = 0; mt < MTM; mt++)
#pragma unroll
        for (int nt = 0; nt < 4; nt++) acc[mt][nt] = (floatx4){0.f, 0.f, 0.f, 0.f};

    __builtin_amdgcn_s_setprio(1);
    for (int ks = 0; ks < 16; ks++) {
        short8 afr[MTM];
#pragma unroll
        for (int mt = 0; mt < MTM; mt++)
            afr[mt] = *(const short8*)&tile[(mt * 16 + l16) * TS + ks * 32 + quad * 8];
#pragma unroll
        for (int nt = 0; nt < 4; nt++) {
            short8 b = *(const short8*)(bbase3 + (ks * 4 + nt) * 512);
#pragma unroll
            for (int mt = 0; mt < MTM; mt++)
                acc[mt][nt] = __builtin_amdgcn_mfma_f32_16x16x32_bf16(afr[mt], b, acc[mt][nt], 0, 0, 0);
        }
    }
    __builtin_amdgcn_s_setprio(0);
    __syncthreads();   // all stage-3 tile reads done before t overwrites it
    {
        float bh1v[4];
#pragma unroll
        for (int nt = 0; nt < 4; nt++) bh1v[nt] = bh1[wave * 64 + nt * 16 + l16];
#pragma unroll
        for (int mt = 0; mt < MTM; mt++)
#pragma unroll
            for (int r2 = 0; r2 < 4; r2++) {
                int row = mt * 16 + quad * 4 + r2;
                float f[4];
#pragma unroll
                for (int nt = 0; nt < 4; nt++) {
                    float v = acc[mt][nt][r2] + bh1v[nt];
                    f[nt] = (v > 0.f) ? v : 0.f;
                }
                uintx2 up = {cvtpk(f[0], f[1]), cvtpk(f[2], f[3])};
                // permuted t-layout: col' = wave*64 + l16*4 + nt  (value is t[d=nt*16+l16])
                *(uintx2*)&tile[row * TS + wave * 64 + l16 * 4] = up;
            }
    }
    __syncthreads();

    // ===== stage 4: per-row head select, logits, softmax (4 threads/row) =====
    // permuted t-layout: thread `is` covers l16 in [4is, 4is+4), nt 0..3 ->
    // 16 contiguous shorts at col' = kk*64 + 16*is; element e maps to
    // d(e) = (e&3)*16 + 4*is + (e>>2)  (ta), d+2 (tb).
    {
        int r = tid >> 2, is = tid & 3;          // r in 0..63, all rows valid (MT=64)
        int grow = blk0 + r;
        int kk = 2 * x[grow] + y[grow];
        const short* tp = &tile[r * TS + kk * 64 + is * 16];
        short8 ta = *(const short8*)tp;
        short8 tb = *(const short8*)(tp + 8);
        const float* wp = Wh2 + kk * 256;
        float lg0 = 0.f, lg1 = 0.f, lg2 = 0.f, lg3 = 0.f;
#pragma unroll
        for (int e = 0; e < 8; e++) {
            int d0 = (e & 3) * 16 + 4 * is + (e >> 2);
            float t0 = bf2f(ta[e]);
            floatx4 w0 = *(const floatx4*)(wp + d0 * 4);
            float t1 = bf2f(tb[e]);
            floatx4 w1 = *(const floatx4*)(wp + (d0 + 2) * 4);
            lg0 += t0 * w0[0] + t1 * w1[0];
            lg1 += t0 * w0[1] + t1 * w1[1];
            lg2 += t0 * w0[2] + t1 * w1[2];
            lg3 += t0 * w0[3] + t1 * w1[3];
        }
#pragma unroll
        for (int off = 1; off < 4; off <<= 1) {
            lg0 += __shfl_xor(lg0, off, 64);
            lg1 += __shfl_xor(lg1, off, 64);
            lg2 += __shfl_xor(lg2, off, 64);
            lg3 += __shfl_xor(lg3, off, 64);
        }
        if (is == 0) {
            lg0 += bh2[kk * 4 + 0]; lg1 += bh2[kk * 4 + 1];
            lg2 += bh2[kk * 4 + 2]; lg3 += bh2[kk * 4 + 3];
            float m = fmaxf(fmaxf(lg0, lg1), fmaxf(lg2, lg3));
            float e0 = __expf(lg0 - m), e1 = __expf(lg1 - m);
            float e2 = __expf(lg2 - m), e3 = __expf(lg3 - m);
            float inv = 1.f / (e0 + e1 + e2 + e3);
            floatx4 o = {e0 * inv, e1 * inv, e2 * inv, e3 * inv};
            *(floatx4*)(out + grow * 4) = o;
        }
    }
}

extern "C" void kernel_launch(void* const* d_in, const int* in_sizes, int n_in,
                              void* d_out, int out_size, void* d_ws, size_t ws_size,
                              hipStream_t stream) {
    const float* z   = (const float*)d_in[0];
    const int*   x   = (const int*)d_in[1];
    const int*   y   = (const int*)d_in[2];
    const float* W1  = (const float*)d_in[3];
    const float* b1  = (const float*)d_in[4];
    const float* g1  = (const float*)d_in[5];
    const float* be1 = (const float*)d_in[6];
    const float* W2  = (const float*)d_in[7];
    const float* b2  = (const float*)d_in[8];
    const float* g2  = (const float*)d_in[9];
    const float* be2 = (const float*)d_in[10];
    const float* Wh1 = (const float*)d_in[11];
    const float* bh1 = (const float*)d_in[12];
    const float* Wh2 = (const float*)d_in[13];
    const float* bh2 = (const float*)d_in[14];
    short* ws = (short*)d_ws;
    float* out = (float*)d_out;

    hipLaunchKernelGGL(convert_weights, dim3(1664), dim3(256), 0, stream, W1, W2, Wh1, ws);
    hipLaunchKernelGGL(fused_kernel, dim3(NROWS / MT), dim3(256), 0, stream,
                       z, x, y, b1, g1, be1, b2, g2, be2, bh1, Wh2, bh2,
                       (const short*)ws, out);
}